// Round 6
// baseline (181.568 us; speedup 1.0000x reference)
//
#include <hip/hip_runtime.h>
#include <hip/hip_bf16.h>

typedef __attribute__((ext_vector_type(8))) short short8;
typedef __attribute__((ext_vector_type(4))) float f32x4;

// Problem constants (from reference)
constexpr int NN = 50000;   // nodes
constexpr int NE = 800000;  // edges
constexpr int FN = 64;      // node feat
constexpr int FE = 32;      // edge feat
constexpr int FG = 32;      // global feat
constexpr int OD = 64;      // out dim
constexpr int NG = 256;     // graphs

constexpr int SCAN_B = 256;
constexpr int NBLK = (NN + SCAN_B - 1) / SCAN_B;  // 196

constexpr int SLOTS_MAX = NE + 15 * NN;           // 1.55M padded bucket slots
constexpr int AGG_BLOCKS = 1280;                  // 5 blocks/CU at ~96 VGPR
constexpr int AGG_WAVES  = AGG_BLOCKS * 4;        // 5120 waves
constexpr int NWIN       = NN / 16;               // 3125 node-windows (exact)
constexpr int NODE_BLOCKS = 782;                  // ~1 window per wave
constexpr int NODE_WAVES  = NODE_BLOCKS * 4;

static __device__ __forceinline__ unsigned pack_bf16(float a, float b) {
    __hip_bfloat162 h = __float22bfloat162_rn(float2{a, b});
    return *reinterpret_cast<unsigned*>(&h);
}
static __device__ __forceinline__ float bf16r(float v) {
    __hip_bfloat16 h = __float2bfloat16(v);
    return __bfloat162float(h);
}

// ---------------------------------------------------------------------------
// x (f32) -> x_bf16 table (50000 x 64); also zeroes pad row NN.
// ---------------------------------------------------------------------------
__global__ __launch_bounds__(256) void k_xcvt(const float* __restrict__ x,
                                              unsigned* __restrict__ xb32) {
    const int i = blockIdx.x * 256 + threadIdx.x;  // per 8 elements
    if (i < 32 && blockIdx.x == 0) xb32[NN * 32 + i] = 0;  // zero row NN
    if (i >= NN * FN / 8) return;
    const float4* p = (const float4*)(x + (size_t)i * 8);
    float4 f0 = p[0], f1 = p[1];
    uint4 o;
    o.x = pack_bf16(f0.x, f0.y);
    o.y = pack_bf16(f0.z, f0.w);
    o.z = pack_bf16(f1.x, f1.y);
    o.w = pack_bf16(f1.z, f1.w);
    ((uint4*)xb32)[i] = o;
}

// ---------------------------------------------------------------------------
// Precompute: uW2b[g][j] = b2[j] + u[g]·W2_u[:,j]  (blocks 0..63, exact f32)
//             corr[j] = relu(bf16(ea[0])·bf16(W1_bot[:,j]) + b1[j]) (block 64)
// ---------------------------------------------------------------------------
__global__ __launch_bounds__(256) void k_pre(const float* __restrict__ u,
                                             const float* __restrict__ W2,
                                             const float* __restrict__ b2,
                                             const float* __restrict__ ea,
                                             const float* __restrict__ W1,
                                             const float* __restrict__ b1,
                                             float* __restrict__ uW2b,
                                             float* __restrict__ corr) {
    if (blockIdx.x == NG / 4) {  // corr block
        const int j = threadIdx.x;
        if (j < OD) {
            float acc = b1[j];
#pragma unroll
            for (int k = 0; k < FE; ++k) {
                const float ek = bf16r(ea[k]);
                const float wk = bf16r(W1[(FN + k) * OD + j]);
                acc = fmaf(ek, wk, acc);
            }
            corr[j] = fmaxf(acc, 0.0f);
        }
        return;
    }
    const int lane = threadIdx.x & 63;
    float wcol[FG];
#pragma unroll
    for (int k = 0; k < FG; ++k) wcol[k] = W2[(FN + OD + k) * OD + lane];
    const float bias = b2[lane];

    int g = (blockIdx.x * blockDim.x + threadIdx.x) >> 6;
    g = __builtin_amdgcn_readfirstlane(g);
    if (g >= NG) return;

    const float* __restrict__ urow = u + (size_t)g * FG;
    float acc = bias;
#pragma unroll
    for (int k = 0; k < FG; ++k) acc = fmaf(urow[k], wcol[k], acc);
    uW2b[(size_t)g * OD + lane] = acc;
}

// ---------------------------------------------------------------------------
// Bucketing: histogram, scan over PADDED counts (ceil16), scatter, pad-fill.
// ---------------------------------------------------------------------------
__global__ __launch_bounds__(256) void k_hist(const int* __restrict__ ei,
                                              int* __restrict__ cnt) {
    const int e = blockIdx.x * blockDim.x + threadIdx.x;
    if (e < NE) atomicAdd(&cnt[ei[e]], 1);
}

__global__ __launch_bounds__(SCAN_B) void k_scan1(const int* __restrict__ cnt,
                                                  int* __restrict__ pstart,
                                                  int* __restrict__ bsum) {
    __shared__ int lds[SCAN_B];
    const int i = blockIdx.x * SCAN_B + threadIdx.x;
    const int v = (i < NN) ? (((cnt[i] + 15) >> 4) << 4) : 0;  // padded count
    lds[threadIdx.x] = v;
    __syncthreads();
#pragma unroll
    for (int off = 1; off < SCAN_B; off <<= 1) {
        int t = (threadIdx.x >= off) ? lds[threadIdx.x - off] : 0;
        __syncthreads();
        lds[threadIdx.x] += t;
        __syncthreads();
    }
    const int incl = lds[threadIdx.x];
    if (i < NN) pstart[i] = incl - v;  // exclusive within block
    if (threadIdx.x == SCAN_B - 1) bsum[blockIdx.x] = incl;
}

__global__ __launch_bounds__(SCAN_B) void k_scan2(const int* __restrict__ bsum,
                                                  int* __restrict__ bscan) {
    __shared__ int lds[SCAN_B];
    const int i = threadIdx.x;
    const int v = (i < NBLK) ? bsum[i] : 0;
    lds[i] = v;
    __syncthreads();
#pragma unroll
    for (int off = 1; off < SCAN_B; off <<= 1) {
        int t = (i >= off) ? lds[i - off] : 0;
        __syncthreads();
        lds[i] += t;
        __syncthreads();
    }
    if (i < NBLK) bscan[i] = lds[i] - v;
}

__global__ __launch_bounds__(SCAN_B) void k_scan3(int* __restrict__ pstart,
                                                  const int* __restrict__ bscan,
                                                  const int* __restrict__ cnt,
                                                  int* __restrict__ cursor) {
    const int i = blockIdx.x * SCAN_B + threadIdx.x;
    if (i < NN) {
        const int s = pstart[i] + bscan[blockIdx.x];
        pstart[i] = s;
        cursor[i] = s;
        if (i == NN - 1) pstart[NN] = s + (((cnt[i] + 15) >> 4) << 4);
    }
}

__global__ __launch_bounds__(256) void k_scatter(const int* __restrict__ ei,
                                                 int* __restrict__ cursor,
                                                 int2* __restrict__ bucket) {
    const int e = blockIdx.x * blockDim.x + threadIdx.x;
    if (e < NE) {
        const int dst = ei[e];
        const int src = ei[NE + e];
        const int pos = atomicAdd(&cursor[dst], 1);
        bucket[pos] = make_int2(src, e);
    }
}

// Fill only the pad tail of each node's bucket (<=15 slots). Runs in
// parallel with k_scatter (disjoint slots: pads occupy [pstart+cnt, pend)).
__global__ __launch_bounds__(256) void k_padfill(const int* __restrict__ pstart,
                                                 const int* __restrict__ cnt,
                                                 int2* __restrict__ bucket) {
    const int l = threadIdx.x & 63;
    int n = (blockIdx.x * blockDim.x + threadIdx.x) >> 6;
    n = __builtin_amdgcn_readfirstlane(n);
    if (n >= NN) return;
    const int base = pstart[n] + cnt[n];
    const int pads = pstart[n + 1] - base;
    if (l < pads) bucket[base + l] = make_int2(NN, 0);  // zero x-row, ea[0]
}

// ---------------------------------------------------------------------------
// Window-parallel MFMA with explicit 2-deep software pipeline:
//   iter body: (1) prefetch bucket entry 2 windows ahead,
//              (2) issue A-frag gathers for next window,
//              (3) MFMA + reduce + store current window (regs already loaded).
// partial[w][j] = sum_r relu( [x_bf16[src_r] | ea_r] @ W1 + b1 )[j]
// Fragment layouts (mfma_f32_16x16x32_bf16):
//   A: row = lane&15, k = 8*(lane>>4)+i ; B: col = lane&15, same k
//   C: col = lane&15, row = (lane>>4)*4 + q   [measured m89]
// ---------------------------------------------------------------------------
__global__ __launch_bounds__(256) void k_aggw(const int2* __restrict__ bucket,
                                              const float* __restrict__ ea,
                                              const unsigned short* __restrict__ xb,
                                              const float* __restrict__ W1,
                                              const float* __restrict__ b1,
                                              const int* __restrict__ pstart,
                                              float* __restrict__ partial) {
    const int l = threadIdx.x & 63;
    const int g = l >> 4;
    const int c = l & 15;

    // W1 B-fragments: wf[t][b] covers k = 32t.., cols 16b..16b+15
    short8 wf[3][4];
#pragma unroll
    for (int t = 0; t < 3; ++t)
#pragma unroll
        for (int b = 0; b < 4; ++b)
#pragma unroll
            for (int i = 0; i < 8; i += 2) {
                const int k = 32 * t + 8 * g + i;
                const unsigned p = pack_bf16(W1[k * OD + (c + 16 * b)],
                                             W1[(k + 1) * OD + (c + 16 * b)]);
                ((unsigned*)&wf[t][b])[i / 2] = p;
            }
    float bias[4];
#pragma unroll
    for (int b = 0; b < 4; ++b) bias[b] = b1[c + 16 * b];

    const int nwin = pstart[NN] >> 4;  // uniform scalar load
    const int last = nwin - 1;

    int wv = (blockIdx.x * blockDim.x + threadIdx.x) >> 6;
    wv = __builtin_amdgcn_readfirstlane(wv);
    if (wv >= nwin) return;

    // --- prologue: load A-frags for window wv; stage se for wv+S ---
    int w = wv;
    uint4 q0, q1;      // x_bf16[src] halves (current window)
    float4 e0, e1;     // ea[e] (current window, f32)
    {
        const int2 se = bucket[(size_t)w * 16 + c];
        const uint4* xr = (const uint4*)(xb + (size_t)se.x * FN);
        q0 = xr[g];
        q1 = xr[4 + g];
        const float4* er = (const float4*)(ea + (size_t)se.y * FE);
        e0 = er[2 * g];
        e1 = er[2 * g + 1];
    }
    int wn1 = w + AGG_WAVES;
    int2 seB = bucket[(size_t)(wn1 > last ? last : wn1) * 16 + c];  // staged

    while (w < nwin) {
        // (1) prefetch se two windows ahead
        int wn2 = w + 2 * AGG_WAVES;
        const int2 seC = bucket[(size_t)(wn2 > last ? last : wn2) * 16 + c];

        // (2) issue next window's A-frag gathers from staged seB
        const uint4* xrn = (const uint4*)(xb + (size_t)seB.x * FN);
        const uint4 q0n = xrn[g];
        const uint4 q1n = xrn[4 + g];
        const float4* ern = (const float4*)(ea + (size_t)seB.y * FE);
        const float4 e0n = ern[2 * g];
        const float4 e1n = ern[2 * g + 1];

        // (3) compute current window from registers
        short8 a0 = *(short8*)&q0;
        short8 a1 = *(short8*)&q1;
        uint4 q2;
        q2.x = pack_bf16(e0.x, e0.y);
        q2.y = pack_bf16(e0.z, e0.w);
        q2.z = pack_bf16(e1.x, e1.y);
        q2.w = pack_bf16(e1.z, e1.w);
        short8 a2 = *(short8*)&q2;

        float sv[4];
#pragma unroll
        for (int b = 0; b < 4; ++b) {
            f32x4 acc = {0.f, 0.f, 0.f, 0.f};
            acc = __builtin_amdgcn_mfma_f32_16x16x32_bf16(a0, wf[0][b], acc, 0, 0, 0);
            acc = __builtin_amdgcn_mfma_f32_16x16x32_bf16(a1, wf[1][b], acc, 0, 0, 0);
            acc = __builtin_amdgcn_mfma_f32_16x16x32_bf16(a2, wf[2][b], acc, 0, 0, 0);
            float s = fmaxf(acc[0] + bias[b], 0.0f) + fmaxf(acc[1] + bias[b], 0.0f)
                    + fmaxf(acc[2] + bias[b], 0.0f) + fmaxf(acc[3] + bias[b], 0.0f);
            s += __shfl_xor(s, 16);
            s += __shfl_xor(s, 32);
            sv[b] = s;
        }
        float v = sv[0];
        v = (g == 1) ? sv[1] : v;
        v = (g == 2) ? sv[2] : v;
        v = (g == 3) ? sv[3] : v;
        partial[(size_t)w * 64 + l] = v;  // l == c + 16g, coalesced

        // rotate pipeline
        q0 = q0n; q1 = q1n; e0 = e0n; e1 = e1n;
        seB = seC;
        w = wn1;
        wn1 = w + AGG_WAVES;
    }
}

// ---------------------------------------------------------------------------
// Reduce windows per node: aggb[n] = bf16( sum partials - pads*corr )
// ---------------------------------------------------------------------------
__global__ __launch_bounds__(256) void k_red(const float* __restrict__ partial,
                                             const int* __restrict__ pstart,
                                             const int* __restrict__ cnt,
                                             const float* __restrict__ corr,
                                             unsigned short* __restrict__ aggb) {
    const int l = threadIdx.x & 63;
    int n = (blockIdx.x * blockDim.x + threadIdx.x) >> 6;
    n = __builtin_amdgcn_readfirstlane(n);
    if (n >= NN) return;

    const int w0 = pstart[n] >> 4;
    const int w1 = pstart[n + 1] >> 4;
    float s = 0.0f;
    for (int w = w0; w < w1; ++w) s += partial[(size_t)w * 64 + l];
    const int pads = ((w1 - w0) << 4) - cnt[n];
    s -= (float)pads * corr[l];
    __hip_bfloat16 hb = __float2bfloat16(s);
    aggb[(size_t)n * OD + l] = *reinterpret_cast<unsigned short*>(&hb);
}

// ---------------------------------------------------------------------------
// Node MLP via MFMA: out = relu([x_bf16 | agg_bf16] @ W2[0:128] + uW2b[batch])
// ---------------------------------------------------------------------------
__global__ __launch_bounds__(256) void k_nodem(const unsigned short* __restrict__ xb,
                                               const unsigned short* __restrict__ aggb,
                                               const int* __restrict__ bat,
                                               const float* __restrict__ uW2b,
                                               const float* __restrict__ W2,
                                               float* __restrict__ out) {
    const int l = threadIdx.x & 63;
    const int g = l >> 4;
    const int c = l & 15;

    short8 wf[4][4];
#pragma unroll
    for (int t = 0; t < 4; ++t)
#pragma unroll
        for (int b = 0; b < 4; ++b)
#pragma unroll
            for (int i = 0; i < 8; i += 2) {
                const int k = 32 * t + 8 * g + i;
                const unsigned p = pack_bf16(W2[k * OD + (c + 16 * b)],
                                             W2[(k + 1) * OD + (c + 16 * b)]);
                ((unsigned*)&wf[t][b])[i / 2] = p;
            }

    int wv = (blockIdx.x * blockDim.x + threadIdx.x) >> 6;
    wv = __builtin_amdgcn_readfirstlane(wv);

    for (int w = wv; w < NWIN; w += NODE_WAVES) {
        const int n0 = w * 16;
        const uint4* xr = (const uint4*)(xb + (size_t)(n0 + c) * FN);
        const uint4* ar = (const uint4*)(aggb + (size_t)(n0 + c) * OD);
        uint4 qx0 = xr[g], qx1 = xr[4 + g];
        uint4 qa0 = ar[g], qa1 = ar[4 + g];
        short8 a0 = *(short8*)&qx0, a1 = *(short8*)&qx1;
        short8 a2 = *(short8*)&qa0, a3 = *(short8*)&qa1;

        int bq[4];
#pragma unroll
        for (int q = 0; q < 4; ++q) bq[q] = bat[n0 + g * 4 + q];

#pragma unroll
        for (int b = 0; b < 4; ++b) {
            f32x4 acc = {0.f, 0.f, 0.f, 0.f};
            acc = __builtin_amdgcn_mfma_f32_16x16x32_bf16(a0, wf[0][b], acc, 0, 0, 0);
            acc = __builtin_amdgcn_mfma_f32_16x16x32_bf16(a1, wf[1][b], acc, 0, 0, 0);
            acc = __builtin_amdgcn_mfma_f32_16x16x32_bf16(a2, wf[2][b], acc, 0, 0, 0);
            acc = __builtin_amdgcn_mfma_f32_16x16x32_bf16(a3, wf[3][b], acc, 0, 0, 0);
#pragma unroll
            for (int q = 0; q < 4; ++q) {
                const int n = n0 + g * 4 + q;
                const float val = acc[q] + uW2b[(size_t)bq[q] * OD + c + 16 * b];
                out[(size_t)n * OD + c + 16 * b] = fmaxf(val, 0.0f);
            }
        }
    }
}

// ---------------------------------------------------------------------------
extern "C" void kernel_launch(void* const* d_in, const int* in_sizes, int n_in,
                              void* d_out, int out_size, void* d_ws, size_t ws_size,
                              hipStream_t stream) {
    const float* x    = (const float*)d_in[0];   // (50000, 64)
    const int*   ei   = (const int*)d_in[1];     // (2, 800000)
    const float* ea   = (const float*)d_in[2];   // (800000, 32)
    const float* u    = (const float*)d_in[3];   // (256, 32)
    const int*   bat  = (const int*)d_in[4];     // (50000,)
    const float* W1   = (const float*)d_in[5];   // (96, 64)
    const float* b1   = (const float*)d_in[6];   // (64,)
    const float* W2   = (const float*)d_in[7];   // (160, 64)
    const float* b2   = (const float*)d_in[8];   // (64,)
    float* out = (float*)d_out;                  // (50000, 64)

    // workspace layout (~51 MB)
    char* ws = (char*)d_ws;
    auto alloc = [&](size_t bytes) {
        char* p = ws;
        ws += (bytes + 255) & ~size_t(255);
        return p;
    };
    unsigned short* xb   = (unsigned short*)alloc((size_t)(NN + 1) * FN * 2); // +zero row
    unsigned short* aggb = (unsigned short*)alloc((size_t)NN * OD * 2);
    float* uW2b    = (float*)alloc((size_t)NG * OD * sizeof(float));
    float* corr    = (float*)alloc((size_t)OD * sizeof(float));
    int*   cnt     = (int*)alloc((size_t)NN * sizeof(int));
    int*   pstart  = (int*)alloc((size_t)(NN + 1) * sizeof(int));
    int*   cursor  = (int*)alloc((size_t)NN * sizeof(int));
    int*   bsum    = (int*)alloc((size_t)NBLK * sizeof(int));
    int*   bscan   = (int*)alloc((size_t)NBLK * sizeof(int));
    int2*  bucket  = (int2*)alloc((size_t)SLOTS_MAX * sizeof(int2));          // 12.4 MB
    float* partial = (float*)alloc((size_t)(SLOTS_MAX / 16) * OD * sizeof(float)); // 24.8 MB

    hipMemsetAsync(cnt, 0, (size_t)NN * sizeof(int), stream);

    // precomputes
    k_xcvt<<<dim3((NN * FN / 8 + 255) / 256), dim3(256), 0, stream>>>(x, (unsigned*)xb);
    k_pre<<<dim3(NG / 4 + 1), dim3(256), 0, stream>>>(u, W2, b2, ea, W1, b1, uW2b, corr);

    // bucket edges by destination (padded offsets)
    k_hist<<<dim3((NE + 255) / 256), dim3(256), 0, stream>>>(ei, cnt);
    k_scan1<<<dim3(NBLK), dim3(SCAN_B), 0, stream>>>(cnt, pstart, bsum);
    k_scan2<<<dim3(1), dim3(SCAN_B), 0, stream>>>(bsum, bscan);
    k_scan3<<<dim3(NBLK), dim3(SCAN_B), 0, stream>>>(pstart, bscan, cnt, cursor);
    k_scatter<<<dim3((NE + 255) / 256), dim3(256), 0, stream>>>(ei, cursor, bucket);
    k_padfill<<<dim3((NN * 64 + 255) / 256), dim3(256), 0, stream>>>(pstart, cnt, bucket);

    // window-parallel MFMA (software-pipelined) + per-node reduce
    k_aggw<<<dim3(AGG_BLOCKS), dim3(256), 0, stream>>>(bucket, ea, xb, W1, b1, pstart, partial);
    k_red<<<dim3((NN * 64 + 255) / 256), dim3(256), 0, stream>>>(partial, pstart, cnt, corr, aggb);

    // node MLP (MFMA)
    k_nodem<<<dim3(NODE_BLOCKS), dim3(256), 0, stream>>>(xb, aggb, bat, uW2b, W2, out);
}

// Round 7
// 154.649 us; speedup vs baseline: 1.1741x; 1.1741x over previous
//
#include <hip/hip_runtime.h>
#include <hip/hip_bf16.h>
#include <hip/hip_fp16.h>

typedef __attribute__((ext_vector_type(8))) short short8;
typedef __attribute__((ext_vector_type(4))) float f32x4;

// Problem constants (from reference)
constexpr int NN = 50000;   // nodes
constexpr int NE = 800000;  // edges
constexpr int FN = 64;      // node feat
constexpr int FE = 32;      // edge feat
constexpr int FG = 32;      // global feat
constexpr int OD = 64;      // out dim
constexpr int NG = 256;     // graphs

constexpr int SCAN_B = 256;
constexpr int NBLK = (NN + SCAN_B - 1) / SCAN_B;  // 196

constexpr int NWIN_E = NE / 16;                   // 50000 edge windows (exact)
constexpr int MS_BLOCKS = 2048;
constexpr int MS_WAVES  = MS_BLOCKS * 4;          // 8192 waves, ~6 windows each
constexpr int NWIN_N = NN / 16;                   // 3125 node windows (exact)
constexpr int NODE_BLOCKS = 782;
constexpr int NODE_WAVES  = NODE_BLOCKS * 4;

static __device__ __forceinline__ unsigned pack_bf16(float a, float b) {
    __hip_bfloat162 h = __float22bfloat162_rn(float2{a, b});
    return *reinterpret_cast<unsigned*>(&h);
}

// ---------------------------------------------------------------------------
// x (f32) -> x_bf16 table (50000 x 64)
// ---------------------------------------------------------------------------
__global__ __launch_bounds__(256) void k_xcvt(const float* __restrict__ x,
                                              unsigned* __restrict__ xb32) {
    const int i = blockIdx.x * 256 + threadIdx.x;  // per 8 elements
    if (i >= NN * FN / 8) return;
    const float4* p = (const float4*)(x + (size_t)i * 8);
    float4 f0 = p[0], f1 = p[1];
    uint4 o;
    o.x = pack_bf16(f0.x, f0.y);
    o.y = pack_bf16(f0.z, f0.w);
    o.z = pack_bf16(f1.x, f1.y);
    o.w = pack_bf16(f1.z, f1.w);
    ((uint4*)xb32)[i] = o;
}

// ---------------------------------------------------------------------------
// uW2b[g][j] = b2[j] + u[g]·W2_u[:,j]   (exact f32)
// ---------------------------------------------------------------------------
__global__ __launch_bounds__(256) void k_uw2(const float* __restrict__ u,
                                             const float* __restrict__ W2,
                                             const float* __restrict__ b2,
                                             float* __restrict__ uW2b) {
    const int lane = threadIdx.x & 63;
    float wcol[FG];
#pragma unroll
    for (int k = 0; k < FG; ++k) wcol[k] = W2[(FN + OD + k) * OD + lane];
    const float bias = b2[lane];

    int g = (blockIdx.x * blockDim.x + threadIdx.x) >> 6;
    g = __builtin_amdgcn_readfirstlane(g);
    if (g >= NG) return;

    const float* __restrict__ urow = u + (size_t)g * FG;
    float acc = bias;
#pragma unroll
    for (int k = 0; k < FG; ++k) acc = fmaf(urow[k], wcol[k], acc);
    uW2b[(size_t)g * OD + lane] = acc;
}

// ---------------------------------------------------------------------------
// Histogram of dst + 3-step exclusive scan (unpadded counts).
// ---------------------------------------------------------------------------
__global__ __launch_bounds__(256) void k_hist(const int* __restrict__ ei,
                                              int* __restrict__ cnt) {
    const int e = blockIdx.x * blockDim.x + threadIdx.x;
    if (e < NE) atomicAdd(&cnt[ei[e]], 1);
}

__global__ __launch_bounds__(SCAN_B) void k_scan1(const int* __restrict__ cnt,
                                                  int* __restrict__ start,
                                                  int* __restrict__ bsum) {
    __shared__ int lds[SCAN_B];
    const int i = blockIdx.x * SCAN_B + threadIdx.x;
    const int v = (i < NN) ? cnt[i] : 0;
    lds[threadIdx.x] = v;
    __syncthreads();
#pragma unroll
    for (int off = 1; off < SCAN_B; off <<= 1) {
        int t = (threadIdx.x >= off) ? lds[threadIdx.x - off] : 0;
        __syncthreads();
        lds[threadIdx.x] += t;
        __syncthreads();
    }
    const int incl = lds[threadIdx.x];
    if (i < NN) start[i] = incl - v;  // exclusive within block
    if (threadIdx.x == SCAN_B - 1) bsum[blockIdx.x] = incl;
}

__global__ __launch_bounds__(SCAN_B) void k_scan2(const int* __restrict__ bsum,
                                                  int* __restrict__ bscan) {
    __shared__ int lds[SCAN_B];
    const int i = threadIdx.x;
    const int v = (i < NBLK) ? bsum[i] : 0;
    lds[i] = v;
    __syncthreads();
#pragma unroll
    for (int off = 1; off < SCAN_B; off <<= 1) {
        int t = (i >= off) ? lds[i - off] : 0;
        __syncthreads();
        lds[i] += t;
        __syncthreads();
    }
    if (i < NBLK) bscan[i] = lds[i] - v;
}

__global__ __launch_bounds__(SCAN_B) void k_scan3(int* __restrict__ start,
                                                  const int* __restrict__ bscan,
                                                  const int* __restrict__ cnt,
                                                  int* __restrict__ cursor) {
    const int i = blockIdx.x * SCAN_B + threadIdx.x;
    if (i < NN) {
        const int s = start[i] + bscan[blockIdx.x];
        start[i] = s;
        cursor[i] = s;
        if (i == NN - 1) start[NN] = s + cnt[i];  // == NE
    }
}

// ---------------------------------------------------------------------------
// Edge-major message computation + scatter (ALL reads coalesced except the
// small L2/L3-resident xb table):
//   window = 16 consecutive edges; msg = relu([x_bf16[src] | ea] @ W1 + b1)
//   slot = atomic cursor[dst]; store msg row as f16 into mbuf[slot]
//   (column-permuted layout: f16 index slot*64 + c*4 + b holds col c+16b,
//    so each lane's 4 values for a row are one contiguous 8 B store).
// Fragment layouts (mfma_f32_16x16x32_bf16), verified rounds 2-5:
//   A: row = lane&15, k = 8*(lane>>4)+i ; B: col = lane&15, same k
//   C: col = lane&15, row = (lane>>4)*4 + q
// ---------------------------------------------------------------------------
__global__ __launch_bounds__(256) void k_msgscat(const int* __restrict__ ei,
                                                 const float* __restrict__ ea,
                                                 const unsigned short* __restrict__ xb,
                                                 const float* __restrict__ W1,
                                                 const float* __restrict__ b1,
                                                 int* __restrict__ cursor,
                                                 unsigned short* __restrict__ mbuf) {
    const int l = threadIdx.x & 63;
    const int g = l >> 4;
    const int c = l & 15;

    // W1 B-fragments: wf[t][b] covers k = 32t.., cols 16b..16b+15
    short8 wf[3][4];
#pragma unroll
    for (int t = 0; t < 3; ++t)
#pragma unroll
        for (int b = 0; b < 4; ++b)
#pragma unroll
            for (int i = 0; i < 8; i += 2) {
                const int k = 32 * t + 8 * g + i;
                const unsigned p = pack_bf16(W1[k * OD + (c + 16 * b)],
                                             W1[(k + 1) * OD + (c + 16 * b)]);
                ((unsigned*)&wf[t][b])[i / 2] = p;
            }
    float bias[4];
#pragma unroll
    for (int b = 0; b < 4; ++b) bias[b] = b1[c + 16 * b];

    int wv = (blockIdx.x * blockDim.x + threadIdx.x) >> 6;
    wv = __builtin_amdgcn_readfirstlane(wv);

    for (int w = wv; w < NWIN_E; w += MS_WAVES) {
        const int e = w * 16 + c;            // this lane's edge (dup over g)
        const int dst = ei[e];               // coalesced
        const int src = ei[NE + e];          // coalesced
        int pos = 0;
        if (l < 16) pos = atomicAdd(&cursor[dst], 1);

        // A fragments: chunks 0,1 = x_bf16[src] (gather), chunk 2 = cvt(ea[e])
        short8 a0, a1, a2;
        {
            const uint4* xr = (const uint4*)(xb + (size_t)src * FN);
            uint4 q0 = xr[g];
            uint4 q1 = xr[4 + g];
            a0 = *(short8*)&q0;
            a1 = *(short8*)&q1;
        }
        {
            const float4* er = (const float4*)(ea + (size_t)e * FE);  // coalesced
            float4 e0 = er[2 * g], e1 = er[2 * g + 1];
            uint4 q2;
            q2.x = pack_bf16(e0.x, e0.y);
            q2.y = pack_bf16(e0.z, e0.w);
            q2.z = pack_bf16(e1.x, e1.y);
            q2.w = pack_bf16(e1.z, e1.w);
            a2 = *(short8*)&q2;
        }

        f32x4 accb[4];
#pragma unroll
        for (int b = 0; b < 4; ++b) {
            f32x4 acc = {0.f, 0.f, 0.f, 0.f};
            acc = __builtin_amdgcn_mfma_f32_16x16x32_bf16(a0, wf[0][b], acc, 0, 0, 0);
            acc = __builtin_amdgcn_mfma_f32_16x16x32_bf16(a1, wf[1][b], acc, 0, 0, 0);
            acc = __builtin_amdgcn_mfma_f32_16x16x32_bf16(a2, wf[2][b], acc, 0, 0, 0);
            accb[b] = acc;
        }

        // store: row r = 4g+q belongs to edge w*16+r; its slot came from lane r
#pragma unroll
        for (int q = 0; q < 4; ++q) {
            const int pr = __shfl(pos, 4 * g + q);  // slot of edge 4g+q
            const float v0 = fmaxf(accb[0][q] + bias[0], 0.0f);
            const float v1 = fmaxf(accb[1][q] + bias[1], 0.0f);
            const float v2 = fmaxf(accb[2][q] + bias[2], 0.0f);
            const float v3 = fmaxf(accb[3][q] + bias[3], 0.0f);
            const __half2 h01 = __float22half2_rn(float2{v0, v1});
            const __half2 h23 = __float22half2_rn(float2{v2, v3});
            uint2 out;
            out.x = *reinterpret_cast<const unsigned*>(&h01);
            out.y = *reinterpret_cast<const unsigned*>(&h23);
            *reinterpret_cast<uint2*>(mbuf + (size_t)pr * 64 + c * 4) = out;
        }
    }
}

// ---------------------------------------------------------------------------
// Segment reduce: aggb[n][col] = bf16( sum over node n's slots of mbuf )
// Purely sequential reads (128 B per row per wave). Lane l owns slot-col l,
// true col = (l>>2) + 16*(l&3)  (un-permute on the aggb write).
// ---------------------------------------------------------------------------
__global__ __launch_bounds__(256) void k_segred(const unsigned short* __restrict__ mbuf,
                                                const int* __restrict__ start,
                                                unsigned short* __restrict__ aggb) {
    const int l = threadIdx.x & 63;
    int n = (blockIdx.x * blockDim.x + threadIdx.x) >> 6;
    n = __builtin_amdgcn_readfirstlane(n);
    if (n >= NN) return;

    const int r0 = start[n];
    const int r1 = start[n + 1];
    const __half* mh = (const __half*)mbuf;

    float s0 = 0.0f, s1 = 0.0f, s2 = 0.0f, s3 = 0.0f;
    int r = r0;
    for (; r + 3 < r1; r += 4) {
        s0 += __half2float(mh[(size_t)(r + 0) * 64 + l]);
        s1 += __half2float(mh[(size_t)(r + 1) * 64 + l]);
        s2 += __half2float(mh[(size_t)(r + 2) * 64 + l]);
        s3 += __half2float(mh[(size_t)(r + 3) * 64 + l]);
    }
    for (; r < r1; ++r) s0 += __half2float(mh[(size_t)r * 64 + l]);
    const float s = (s0 + s1) + (s2 + s3);

    const int tc = (l >> 2) + 16 * (l & 3);  // un-permute column
    __hip_bfloat16 hb = __float2bfloat16(s);
    aggb[(size_t)n * OD + tc] = *reinterpret_cast<unsigned short*>(&hb);
}

// ---------------------------------------------------------------------------
// Node MLP via MFMA: out = relu([x_bf16 | agg_bf16] @ W2[0:128] + uW2b[batch])
// ---------------------------------------------------------------------------
__global__ __launch_bounds__(256) void k_nodem(const unsigned short* __restrict__ xb,
                                               const unsigned short* __restrict__ aggb,
                                               const int* __restrict__ bat,
                                               const float* __restrict__ uW2b,
                                               const float* __restrict__ W2,
                                               float* __restrict__ out) {
    const int l = threadIdx.x & 63;
    const int g = l >> 4;
    const int c = l & 15;

    short8 wf[4][4];
#pragma unroll
    for (int t = 0; t < 4; ++t)
#pragma unroll
        for (int b = 0; b < 4; ++b)
#pragma unroll
            for (int i = 0; i < 8; i += 2) {
                const int k = 32 * t + 8 * g + i;
                const unsigned p = pack_bf16(W2[k * OD + (c + 16 * b)],
                                             W2[(k + 1) * OD + (c + 16 * b)]);
                ((unsigned*)&wf[t][b])[i / 2] = p;
            }

    int wv = (blockIdx.x * blockDim.x + threadIdx.x) >> 6;
    wv = __builtin_amdgcn_readfirstlane(wv);

    for (int w = wv; w < NWIN_N; w += NODE_WAVES) {
        const int n0 = w * 16;
        const uint4* xr = (const uint4*)(xb + (size_t)(n0 + c) * FN);
        const uint4* ar = (const uint4*)(aggb + (size_t)(n0 + c) * OD);
        uint4 qx0 = xr[g], qx1 = xr[4 + g];
        uint4 qa0 = ar[g], qa1 = ar[4 + g];
        short8 a0 = *(short8*)&qx0, a1 = *(short8*)&qx1;
        short8 a2 = *(short8*)&qa0, a3 = *(short8*)&qa1;

        int bq[4];
#pragma unroll
        for (int q = 0; q < 4; ++q) bq[q] = bat[n0 + g * 4 + q];

#pragma unroll
        for (int b = 0; b < 4; ++b) {
            f32x4 acc = {0.f, 0.f, 0.f, 0.f};
            acc = __builtin_amdgcn_mfma_f32_16x16x32_bf16(a0, wf[0][b], acc, 0, 0, 0);
            acc = __builtin_amdgcn_mfma_f32_16x16x32_bf16(a1, wf[1][b], acc, 0, 0, 0);
            acc = __builtin_amdgcn_mfma_f32_16x16x32_bf16(a2, wf[2][b], acc, 0, 0, 0);
            acc = __builtin_amdgcn_mfma_f32_16x16x32_bf16(a3, wf[3][b], acc, 0, 0, 0);
#pragma unroll
            for (int q = 0; q < 4; ++q) {
                const int n = n0 + g * 4 + q;
                const float val = acc[q] + uW2b[(size_t)bq[q] * OD + c + 16 * b];
                out[(size_t)n * OD + c + 16 * b] = fmaxf(val, 0.0f);
            }
        }
    }
}

// ---------------------------------------------------------------------------
extern "C" void kernel_launch(void* const* d_in, const int* in_sizes, int n_in,
                              void* d_out, int out_size, void* d_ws, size_t ws_size,
                              hipStream_t stream) {
    const float* x    = (const float*)d_in[0];   // (50000, 64)
    const int*   ei   = (const int*)d_in[1];     // (2, 800000)
    const float* ea   = (const float*)d_in[2];   // (800000, 32)
    const float* u    = (const float*)d_in[3];   // (256, 32)
    const int*   bat  = (const int*)d_in[4];     // (50000,)
    const float* W1   = (const float*)d_in[5];   // (96, 64)
    const float* b1   = (const float*)d_in[6];   // (64,)
    const float* W2   = (const float*)d_in[7];   // (160, 64)
    const float* b2   = (const float*)d_in[8];   // (64,)
    float* out = (float*)d_out;                  // (50000, 64)

    // workspace layout (~116 MB; mbuf dominates)
    char* ws = (char*)d_ws;
    auto alloc = [&](size_t bytes) {
        char* p = ws;
        ws += (bytes + 255) & ~size_t(255);
        return p;
    };
    unsigned short* xb   = (unsigned short*)alloc((size_t)NN * FN * 2);   // 6.4 MB
    unsigned short* aggb = (unsigned short*)alloc((size_t)NN * OD * 2);   // 6.4 MB
    float* uW2b    = (float*)alloc((size_t)NG * OD * sizeof(float));
    int*   cnt     = (int*)alloc((size_t)NN * sizeof(int));
    int*   start   = (int*)alloc((size_t)(NN + 1) * sizeof(int));
    int*   cursor  = (int*)alloc((size_t)NN * sizeof(int));
    int*   bsum    = (int*)alloc((size_t)NBLK * sizeof(int));
    int*   bscan   = (int*)alloc((size_t)NBLK * sizeof(int));
    unsigned short* mbuf = (unsigned short*)alloc((size_t)NE * OD * 2);   // 102.4 MB

    hipMemsetAsync(cnt, 0, (size_t)NN * sizeof(int), stream);

    // precomputes
    k_xcvt<<<dim3((NN * FN / 8 + 255) / 256), dim3(256), 0, stream>>>(x, (unsigned*)xb);
    k_uw2<<<dim3((NG * 64 + 255) / 256), dim3(256), 0, stream>>>(u, W2, b2, uW2b);

    // dst histogram + exclusive scan
    k_hist<<<dim3((NE + 255) / 256), dim3(256), 0, stream>>>(ei, cnt);
    k_scan1<<<dim3(NBLK), dim3(SCAN_B), 0, stream>>>(cnt, start, bsum);
    k_scan2<<<dim3(1), dim3(SCAN_B), 0, stream>>>(bsum, bscan);
    k_scan3<<<dim3(NBLK), dim3(SCAN_B), 0, stream>>>(start, bscan, cnt, cursor);

    // edge-major message MFMA + scatter (coalesced reads, random writes)
    k_msgscat<<<dim3(MS_BLOCKS), dim3(256), 0, stream>>>(ei, ea, xb, W1, b1, cursor, mbuf);

    // sequential segment reduce
    k_segred<<<dim3((NN * 64 + 255) / 256), dim3(256), 0, stream>>>(mbuf, start, aggb);

    // node MLP (MFMA)
    k_nodem<<<dim3(NODE_BLOCKS), dim3(256), 0, stream>>>(xb, aggb, bat, uW2b, W2, out);
}